// Round 2
// 107.159 us; speedup vs baseline: 1.0143x; 1.0143x over previous
//
#include <hip/hip_runtime.h>

// SymmetricContraction via symmetrized-basis contraction.
//
// out[n,m,0]   = w0[e,m]*Sum_a S0[a] f_a   + Sum_s w2[e,s,m]*B2_s + Sum_s w4[e,s,m]*B4_s
// out[n,m,1+d] = w1[e,m]*Sum_a S1[a,d] f_a + Sum_s w3[e,s,m]*B3_sd + Sum_s w5[e,s,m]*B5_sd
// where B*_s = Sum_{monomial k} S*[k,s(,d)] * M_k(f), f = feats[n,m,0:9],
// monomials: 45 quads (a<=b), 165 cubics (a<=b<=c), S* = permutation-symmetrized bases.
//
// R5 -> R6: k_eval was still fetch/latency-bound: per-wave s_load streams of the
// shared 10KB S-table dominate (only ~20 dwordx4 in flight under SGPR budget;
// each cubic record feeds just 10 FMAs). Amortize: each thread now owns TWO m
// values (m, m+64). Every S-record load feeds 2x FMA work; per-wave scalar
// fetch traffic halves. Block 256 = 2 nodes x 64 m-pairs x 2 K-halves
// (half = (tid>>6)&1, wave-uniform). Grid 1024 = 4 blocks/CU = 16 waves/CU.
// __launch_bounds__(256,4): VGPR cap 128 (live set ~90, no spill).
//
// (R6 resubmission: previous round hit GPUAcquisitionTimeout; no measurement.)
//
// Output row layout (512 floats): [0..127]=d0 per m ; [128+3m+d] = vector part.

#define N_NODES 2048
#define MUL     128
#define NROW    1152
#define NQ      45
#define NC      165
#define KSPLIT  57      // cubic split point between half0 / half1
// float4-unit layout of S: [0,9) linear recs (pad to 12), [12,147) quad recs
// (45 x 3), [147,642) cubic recs (165 x 3).
#define Q4_BASE 12
#define C4_BASE 147
#define S4_TOTAL 642   // float4s -> 10272 bytes (d_ws usage)

// ---------------------------------------------------------------------------
// Kernel 1: build symmetrized basis table S into d_ws. One block, 256 threads.
// ---------------------------------------------------------------------------
__global__ void k_prep(const float* __restrict__ b0, const float* __restrict__ b1,
                       const float* __restrict__ b2, const float* __restrict__ b3,
                       const float* __restrict__ b4, const float* __restrict__ b5,
                       float4* __restrict__ S) {
    const int t = threadIdx.x;
    if (t < 9) {
        S[t] = make_float4(b0[t], b1[t * 3 + 0], b1[t * 3 + 1], b1[t * 3 + 2]);
    } else if (t < Q4_BASE) {
        S[t] = make_float4(0.f, 0.f, 0.f, 0.f);   // pad
    } else if (t < Q4_BASE + NQ) {
        const int k = t - Q4_BASE;
        int a = -1, b = -1, kk = k;
        for (int aa = 0; aa < 9 && a < 0; ++aa) {
            const int cnt = 9 - aa;
            if (kk < cnt) { a = aa; b = aa + kk; } else kk -= cnt;
        }
        const float mult = (a == b) ? 0.5f : 1.0f;
        const int i1 = a * 9 + b, i2 = b * 9 + a;
        float s2[3], s3[6];
        for (int s = 0; s < 3; ++s)
            s2[s] = (b2[i1 * 3 + s] + b2[i2 * 3 + s]) * mult;
        for (int s = 0; s < 2; ++s)
            for (int d = 0; d < 3; ++d)
                s3[s * 3 + d] = (b3[(i1 * 2 + s) * 3 + d] + b3[(i2 * 2 + s) * 3 + d]) * mult;
        S[Q4_BASE + k * 3 + 0] = make_float4(s2[0], s2[1], s2[2], 0.f);
        S[Q4_BASE + k * 3 + 1] = make_float4(s3[0], s3[1], s3[2], s3[3]);
        S[Q4_BASE + k * 3 + 2] = make_float4(s3[4], s3[5], 0.f, 0.f);
    } else if (t < Q4_BASE + NQ + NC) {
        const int k = t - Q4_BASE - NQ;
        int a = -1, b = -1, c = -1, kk = k;
        for (int aa = 0; aa < 9 && a < 0; ++aa)
            for (int bb = aa; bb < 9 && a < 0; ++bb) {
                const int cnt = 9 - bb;
                if (kk < cnt) { a = aa; b = bb; c = bb + kk; } else kk -= cnt;
            }
        const float mult = (a == b && b == c) ? (1.0f / 6.0f)
                         : ((a == b || b == c) ? 0.5f : 1.0f);
        int p[6];
        p[0] = (a * 9 + b) * 9 + c;  p[1] = (a * 9 + c) * 9 + b;
        p[2] = (b * 9 + a) * 9 + c;  p[3] = (b * 9 + c) * 9 + a;
        p[4] = (c * 9 + a) * 9 + b;  p[5] = (c * 9 + b) * 9 + a;
        float s4[4], s5[6];
        for (int s = 0; s < 4; ++s) {
            float v = 0.f;
            for (int j = 0; j < 6; ++j) v += b4[p[j] * 4 + s];
            s4[s] = v * mult;
        }
        for (int s = 0; s < 2; ++s)
            for (int d = 0; d < 3; ++d) {
                float v = 0.f;
                for (int j = 0; j < 6; ++j) v += b5[(p[j] * 2 + s) * 3 + d];
                s5[s * 3 + d] = v * mult;
            }
        S[C4_BASE + k * 3 + 0] = make_float4(s4[0], s4[1], s4[2], s4[3]);
        S[C4_BASE + k * 3 + 1] = make_float4(s5[0], s5[1], s5[2], s5[3]);
        S[C4_BASE + k * 3 + 2] = make_float4(s5[4], s5[5], 0.f, 0.f);
    }
}

// ---------------------------------------------------------------------------
// Kernel 2: evaluate, split-K + dual-m. Block = 2 nodes.
//   mp = tid & 63 -> handles m = mp and m+64.
//   half = (tid>>6)&1 (wave-uniform): half0 = linear+quads+cubics[k<57],
//   half1 = cubics[k>=57]. nod = tid>>7 selects node within block.
// S reads through address_space(4) -> s_load; each record feeds 2x FMA work.
// ---------------------------------------------------------------------------
typedef float fvec4 __attribute__((ext_vector_type(4)));

__global__ __launch_bounds__(256, 4) void k_eval(
        const float* __restrict__ nf, const int* __restrict__ species,
        const float* __restrict__ w0, const float* __restrict__ w1,
        const float* __restrict__ w2, const float* __restrict__ w3,
        const float* __restrict__ w4, const float* __restrict__ w5,
        const float* __restrict__ Sg, float* __restrict__ out) {
#if defined(__HIP_DEVICE_COMPILE__)
    typedef const __attribute__((address_space(4))) fvec4* S4cp;
    S4cp S = (S4cp)(unsigned long long)Sg;   // reinterpret into constant AS

    // half1 partials: B4[4],B5[6] per (node-in-block, m); stride 11 words
    // (gcd(11,32)=1 -> conflict-free lane access).
    __shared__ float red[256 * 11];

    const int tid  = threadIdx.x;
    const int mp   = tid & 63;
    const int half = (tid >> 6) & 1;         // wave-uniform
    const int nod  = tid >> 7;               // node within block
    const int n    = (blockIdx.x << 1) | nod;

    const float* __restrict__ row = nf + (size_t)n * NROW;
    const int m0 = mp, m1 = mp + 64;
    float f0[9], f1[9];
    f0[0] = row[m0];
    f1[0] = row[m1];
#pragma unroll
    for (int j = 0; j < 3; ++j) {
        f0[1 + j] = row[128 + 3 * m0 + j];
        f1[1 + j] = row[128 + 3 * m1 + j];
    }
#pragma unroll
    for (int j = 0; j < 5; ++j) {
        f0[4 + j] = row[512 + 5 * m0 + j];
        f1[4 + j] = row[512 + 5 * m1 + j];
    }

    float A0a = 0.f, A0b = 0.f, A1a[3] = {}, A1b[3] = {};
    float B2a[3] = {}, B2b[3] = {}, B3a[6] = {}, B3b[6] = {};
    float B4a[4] = {}, B4b[4] = {}, B5a[6] = {}, B5b[6] = {};

    if (half == 1) {
        // ---- cubics kc >= KSPLIT, both m ----
        int kc = 0;
#pragma unroll
        for (int a = 0; a < 9; ++a) {
#pragma unroll
            for (int b = a; b < 9; ++b) {
                const float qa = f0[a] * f0[b];
                const float qb = f1[a] * f1[b];
#pragma unroll
                for (int c = b; c < 9; ++c) {
                    if (kc >= KSPLIT) {      // compile-time folded per iteration
                        const fvec4 r0 = S[C4_BASE + kc * 3 + 0];
                        const fvec4 r1 = S[C4_BASE + kc * 3 + 1];
                        const fvec4 r2 = S[C4_BASE + kc * 3 + 2];
                        const float ta = qa * f0[c];
                        const float tb = qb * f1[c];
                        B4a[0] += ta * r0.x; B4a[1] += ta * r0.y;
                        B4a[2] += ta * r0.z; B4a[3] += ta * r0.w;
                        B5a[0] += ta * r1.x; B5a[1] += ta * r1.y; B5a[2] += ta * r1.z;
                        B5a[3] += ta * r1.w; B5a[4] += ta * r2.x; B5a[5] += ta * r2.y;
                        B4b[0] += tb * r0.x; B4b[1] += tb * r0.y;
                        B4b[2] += tb * r0.z; B4b[3] += tb * r0.w;
                        B5b[0] += tb * r1.x; B5b[1] += tb * r1.y; B5b[2] += tb * r1.z;
                        B5b[3] += tb * r1.w; B5b[4] += tb * r2.x; B5b[5] += tb * r2.y;
                    }
                    ++kc;
                }
            }
        }
        float* __restrict__ d0 = &red[(nod * 128 + m0) * 11];
#pragma unroll
        for (int j = 0; j < 4; ++j) d0[j] = B4a[j];
#pragma unroll
        for (int j = 0; j < 6; ++j) d0[4 + j] = B5a[j];
        float* __restrict__ d1 = &red[(nod * 128 + m1) * 11];
#pragma unroll
        for (int j = 0; j < 4; ++j) d1[j] = B4b[j];
#pragma unroll
        for (int j = 0; j < 6; ++j) d1[4 + j] = B5b[j];
    } else {
        // ---- linear, both m ----
#pragma unroll
        for (int a = 0; a < 9; ++a) {
            const fvec4 L = S[a];
            A0a    += L.x * f0[a];
            A1a[0] += L.y * f0[a];
            A1a[1] += L.z * f0[a];
            A1a[2] += L.w * f0[a];
            A0b    += L.x * f1[a];
            A1b[0] += L.y * f1[a];
            A1b[1] += L.z * f1[a];
            A1b[2] += L.w * f1[a];
        }
        // ---- quads + cubics kc < KSPLIT, both m ----
        int kq = 0, kc = 0;
#pragma unroll
        for (int a = 0; a < 9; ++a) {
#pragma unroll
            for (int b = a; b < 9; ++b) {
                const float qa = f0[a] * f0[b];
                const float qb = f1[a] * f1[b];
                {
                    const fvec4 r0 = S[Q4_BASE + kq * 3 + 0];
                    const fvec4 r1 = S[Q4_BASE + kq * 3 + 1];
                    const fvec4 r2 = S[Q4_BASE + kq * 3 + 2];
                    B2a[0] += qa * r0.x; B2a[1] += qa * r0.y; B2a[2] += qa * r0.z;
                    B3a[0] += qa * r1.x; B3a[1] += qa * r1.y; B3a[2] += qa * r1.z;
                    B3a[3] += qa * r1.w; B3a[4] += qa * r2.x; B3a[5] += qa * r2.y;
                    B2b[0] += qb * r0.x; B2b[1] += qb * r0.y; B2b[2] += qb * r0.z;
                    B3b[0] += qb * r1.x; B3b[1] += qb * r1.y; B3b[2] += qb * r1.z;
                    B3b[3] += qb * r1.w; B3b[4] += qb * r2.x; B3b[5] += qb * r2.y;
                    ++kq;
                }
#pragma unroll
                for (int c = b; c < 9; ++c) {
                    if (kc < KSPLIT) {       // compile-time folded per iteration
                        const fvec4 r0 = S[C4_BASE + kc * 3 + 0];
                        const fvec4 r1 = S[C4_BASE + kc * 3 + 1];
                        const fvec4 r2 = S[C4_BASE + kc * 3 + 2];
                        const float ta = qa * f0[c];
                        const float tb = qb * f1[c];
                        B4a[0] += ta * r0.x; B4a[1] += ta * r0.y;
                        B4a[2] += ta * r0.z; B4a[3] += ta * r0.w;
                        B5a[0] += ta * r1.x; B5a[1] += ta * r1.y; B5a[2] += ta * r1.z;
                        B5a[3] += ta * r1.w; B5a[4] += ta * r2.x; B5a[5] += ta * r2.y;
                        B4b[0] += tb * r0.x; B4b[1] += tb * r0.y;
                        B4b[2] += tb * r0.z; B4b[3] += tb * r0.w;
                        B5b[0] += tb * r1.x; B5b[1] += tb * r1.y; B5b[2] += tb * r1.z;
                        B5b[3] += tb * r1.w; B5b[4] += tb * r2.x; B5b[5] += tb * r2.y;
                    }
                    ++kc;
                }
            }
        }
    }

    __syncthreads();

    if (half == 0) {
        const int e = species[n];
        float* __restrict__ orow = out + (size_t)n * 512;

#define EPILOG(MM, A0v, A1v, B2v, B3v, B4v, B5v)                               \
        do {                                                                   \
            const float* __restrict__ src = &red[(nod * 128 + (MM)) * 11];     \
            _Pragma("unroll")                                                  \
            for (int j = 0; j < 4; ++j) B4v[j] += src[j];                      \
            _Pragma("unroll")                                                  \
            for (int j = 0; j < 6; ++j) B5v[j] += src[4 + j];                  \
            const float wv0 = w0[e * MUL + (MM)];                              \
            const float wv1 = w1[e * MUL + (MM)];                              \
            float wv2[3], wv3[2], wv4[4], wv5[2];                              \
            _Pragma("unroll")                                                  \
            for (int s = 0; s < 3; ++s) wv2[s] = w2[(e * 3 + s) * MUL + (MM)]; \
            _Pragma("unroll")                                                  \
            for (int s = 0; s < 2; ++s) wv3[s] = w3[(e * 2 + s) * MUL + (MM)]; \
            _Pragma("unroll")                                                  \
            for (int s = 0; s < 4; ++s) wv4[s] = w4[(e * 4 + s) * MUL + (MM)]; \
            _Pragma("unroll")                                                  \
            for (int s = 0; s < 2; ++s) wv5[s] = w5[(e * 2 + s) * MUL + (MM)]; \
            orow[MM] = wv0 * A0v                                               \
                     + wv2[0] * B2v[0] + wv2[1] * B2v[1] + wv2[2] * B2v[2]     \
                     + wv4[0] * B4v[0] + wv4[1] * B4v[1]                       \
                     + wv4[2] * B4v[2] + wv4[3] * B4v[3];                      \
            _Pragma("unroll")                                                  \
            for (int d = 0; d < 3; ++d) {                                      \
                orow[128 + 3 * (MM) + d] = wv1 * A1v[d]                        \
                                         + wv3[0] * B3v[d] + wv3[1] * B3v[3 + d] \
                                         + wv5[0] * B5v[d] + wv5[1] * B5v[3 + d]; \
            }                                                                  \
        } while (0)

        EPILOG(m0, A0a, A1a, B2a, B3a, B4a, B5a);
        EPILOG(m1, A0b, A1b, B2b, B3b, B4b, B5b);
#undef EPILOG
    }
#endif  // __HIP_DEVICE_COMPILE__
}

// ---------------------------------------------------------------------------
extern "C" void kernel_launch(void* const* d_in, const int* in_sizes, int n_in,
                              void* d_out, int out_size, void* d_ws, size_t ws_size,
                              hipStream_t stream) {
    const float* nf      = (const float*)d_in[0];
    const int*   species = (const int*)d_in[1];
    const float* b0 = (const float*)d_in[2];  const float* w0 = (const float*)d_in[3];
    const float* b1 = (const float*)d_in[4];  const float* w1 = (const float*)d_in[5];
    const float* b2 = (const float*)d_in[6];  const float* w2 = (const float*)d_in[7];
    const float* b3 = (const float*)d_in[8];  const float* w3 = (const float*)d_in[9];
    const float* b4 = (const float*)d_in[10]; const float* w4 = (const float*)d_in[11];
    const float* b5 = (const float*)d_in[12]; const float* w5 = (const float*)d_in[13];
    float* out = (float*)d_out;

    float4* S = (float4*)d_ws;   // 642 float4 = 10,272 bytes only

    hipLaunchKernelGGL(k_prep, dim3(1), dim3(256), 0, stream,
                       b0, b1, b2, b3, b4, b5, S);
    // 1024 blocks x 256 threads; block = 2 nodes, 64 m-pairs x 2 K-halves
    hipLaunchKernelGGL(k_eval, dim3(N_NODES / 2), dim3(256), 0, stream,
                       nf, species, w0, w1, w2, w3, w4, w5,
                       (const float*)S, out);
}